// Round 1
// baseline (178.514 us; speedup 1.0000x reference)
//
#include <hip/hip_runtime.h>

// PyFlowODE: Heun integration of dx/dt = G(x0, x, t) with Nadaraya-Watson
// Gaussian RBF retrieval. N=2048 queries (d=8), B=4096 bank, T=16 steps.
//
// Layout: 256 blocks x 512 threads. Each block = 8 waves = 8 queries;
// each wave owns one query, its 64 lanes split the 4096 bank entries
// (64 entries/lane). x0 staged ONCE in LDS (128 KB, lo/hi float4 split so
// ds_read_b128 is conflict-free), reused across all 16 steps.
// Softmax is online in log2 domain with deferred rescale (THR=40).

#define NQ     2048
#define NB     4096
#define DD     8
#define TSTEPS 16
#define BLOCK  512
#define QPB    8      // queries (waves) per block

#if defined(__has_builtin)
#if __has_builtin(__builtin_amdgcn_exp2f)
#define EXP2(x) __builtin_amdgcn_exp2f(x)
#endif
#endif
#ifndef EXP2
#define EXP2(x) exp2f(x)
#endif

// Evaluate G(x, t) for this wave's query. x[8] is wave-uniform (replicated
// in every lane). Result written to Gout[8] (again wave-uniform).
__device__ __forceinline__ void eval_G(const float4* __restrict__ lds_lo,
                                       const float4* __restrict__ lds_hi,
                                       const float* x, float t, int lane,
                                       float* Gout) {
    const float alpha = 1.0f - t;
    // logits in log2 domain: l_b = -0.5*log2(e) * ||x - alpha*x0_b||^2 / t^2
    const float c0 = -0.72134752044448170f / (t * t);

    float m = -1e30f;   // running max (log2 domain), per lane
    float s = 0.0f;     // running sum of 2^(l-m)
    float q[DD];
#pragma unroll
    for (int j = 0; j < DD; ++j) q[j] = 0.0f;

#pragma unroll 2
    for (int k = 0; k < NB / 64; k += 4) {
        float4 lo[4], hi[4];
        float  l[4];
#pragma unroll
        for (int e = 0; e < 4; ++e) {
            const int b = lane + (k + e) * 64;   // consecutive lanes -> consecutive float4s
            lo[e] = lds_lo[b];
            hi[e] = lds_hi[b];
            float z, zz;
            z = fmaf(-alpha, lo[e].x, x[0]); zz = z * z;
            z = fmaf(-alpha, lo[e].y, x[1]); zz = fmaf(z, z, zz);
            z = fmaf(-alpha, lo[e].z, x[2]); zz = fmaf(z, z, zz);
            z = fmaf(-alpha, lo[e].w, x[3]); zz = fmaf(z, z, zz);
            z = fmaf(-alpha, hi[e].x, x[4]); zz = fmaf(z, z, zz);
            z = fmaf(-alpha, hi[e].y, x[5]); zz = fmaf(z, z, zz);
            z = fmaf(-alpha, hi[e].z, x[6]); zz = fmaf(z, z, zz);
            z = fmaf(-alpha, hi[e].w, x[7]); zz = fmaf(z, z, zz);
            l[e] = zz * c0;
        }
        // deferred rescale: only when some lane's batch-max exceeds m+40
        // (2^40 headroom; s <= 4096*2^40 ~ 4.5e15, far below f32 max).
        const float bm = fmaxf(fmaxf(l[0], l[1]), fmaxf(l[2], l[3]));
        if (__any(bm > m + 40.0f)) {        // wave-uniform branch
            const float mn = fmaxf(m, bm);
            const float c = EXP2(m - mn);   // m=-1e30 initially -> c=0, zeroes nothing
            s *= c;
#pragma unroll
            for (int j = 0; j < DD; ++j) q[j] *= c;
            m = mn;
        }
#pragma unroll
        for (int e = 0; e < 4; ++e) {
            const float w = EXP2(l[e] - m);  // underflow to 0 is harmless
            s += w;
            q[0] = fmaf(w, lo[e].x, q[0]);
            q[1] = fmaf(w, lo[e].y, q[1]);
            q[2] = fmaf(w, lo[e].z, q[2]);
            q[3] = fmaf(w, lo[e].w, q[3]);
            q[4] = fmaf(w, hi[e].x, q[4]);
            q[5] = fmaf(w, hi[e].y, q[5]);
            q[6] = fmaf(w, hi[e].z, q[6]);
            q[7] = fmaf(w, hi[e].w, q[7]);
        }
    }

    // ---- cross-lane merge (butterfly; all lanes end with identical totals) ----
    float mw = m;
#pragma unroll
    for (int off = 32; off >= 1; off >>= 1)
        mw = fmaxf(mw, __shfl_xor(mw, off));
    const float c = EXP2(m - mw);
    s *= c;
#pragma unroll
    for (int j = 0; j < DD; ++j) q[j] *= c;
#pragma unroll
    for (int off = 32; off >= 1; off >>= 1) {
        s += __shfl_xor(s, off);
#pragma unroll
        for (int j = 0; j < DD; ++j) q[j] += __shfl_xor(q[j], off);
    }

    const float inv = 1.0f / s;
#pragma unroll
    for (int j = 0; j < DD; ++j)
        Gout[j] = (x[j] - q[j] * inv) / t;
}

__global__ __launch_bounds__(BLOCK, 2) void flow_ode_kernel(
        const float* __restrict__ x1,
        const float* __restrict__ x0,
        float* __restrict__ out) {
    __shared__ float4 lds_lo[NB];   // x0[b][0:4]
    __shared__ float4 lds_hi[NB];   // x0[b][4:8]

    const int tid = threadIdx.x;
    // stage x0 once (128 KB); reused for all 16 steps
    for (int b = tid; b < NB; b += BLOCK) {
        const float4* p = reinterpret_cast<const float4*>(x0) + 2 * b;
        lds_lo[b] = p[0];
        lds_hi[b] = p[1];
    }
    __syncthreads();

    const int wave = tid >> 6;
    const int lane = tid & 63;
    const int n = blockIdx.x * QPB + wave;
    if (n >= NQ) return;

    float xt[DD], G1[DD], G2[DD];
#pragma unroll
    for (int j = 0; j < DD; ++j) xt[j] = x1[n * DD + j];

    // G1 = G(x1, t=1)  (alpha=0 -> uniform weights; handled by generic path)
    eval_G(lds_lo, lds_hi, xt, 1.0f, lane, G1);

    const float h = 0.0625f;        // 1/16, exact
    for (int i = 1; i < TSTEPS; ++i) {
        const float t = 1.0f - h * (float)i;   // exact in f32
        float xe[DD];
#pragma unroll
        for (int j = 0; j < DD; ++j) xe[j] = fmaf(-h, G1[j], xt[j]);  // Euler predictor
        eval_G(lds_lo, lds_hi, xe, t, lane, G2);
#pragma unroll
        for (int j = 0; j < DD; ++j) {
            xt[j] = fmaf(-0.03125f, G1[j] + G2[j], xt[j]);  // xt -= (G1+G2)*h/2
            G1[j] = G2[j];
        }
    }

    if (lane == 0) {
        float4 a, b;
        a.x = xt[0]; a.y = xt[1]; a.z = xt[2]; a.w = xt[3];
        b.x = xt[4]; b.y = xt[5]; b.z = xt[6]; b.w = xt[7];
        float4* o = reinterpret_cast<float4*>(out + n * DD);
        o[0] = a;
        o[1] = b;
    }
}

extern "C" void kernel_launch(void* const* d_in, const int* in_sizes, int n_in,
                              void* d_out, int out_size, void* d_ws, size_t ws_size,
                              hipStream_t stream) {
    const float* x1 = (const float*)d_in[0];   // (2048, 8)
    const float* x0 = (const float*)d_in[1];   // (4096, 8)
    float* out = (float*)d_out;                // (2048, 8)

    const int nblocks = NQ / QPB;              // 256 blocks, 1 per CU
    flow_ode_kernel<<<nblocks, BLOCK, 0, stream>>>(x1, x0, out);
}